// Round 10
// baseline (601.628 us; speedup 1.0000x reference)
//
#include <hip/hip_runtime.h>
#include <math.h>

#define NN 50000
#define EE 800000
#define FIN 128
#define HID 96
#define NL 4

typedef __attribute__((ext_vector_type(8))) short short8;
typedef __attribute__((ext_vector_type(4))) float floatx4;
typedef __attribute__((ext_vector_type(2))) _Float16 half2v;

#define WPREP_L (NL * 2 * 9216)       // 73728
#define WPREP_TOT (WPREP_L + 12288)   // 86016

__device__ __forceinline__ unsigned short f32_to_bf16_rne(float x) {
    unsigned u = __float_as_uint(x);
    unsigned r = (u + 0x7FFFu + ((u >> 16) & 1u)) >> 16;
    return (unsigned short)r;
}
__device__ __forceinline__ float bf16_to_f32(unsigned short h) {
    return __uint_as_float(((unsigned)h) << 16);
}

// ---------------- CSR build ----------------
__global__ void k_hist(const int* __restrict__ dst, int* __restrict__ deg, int E) {
    int e = blockIdx.x * blockDim.x + threadIdx.x;
    if (e < E) atomicAdd(&deg[dst[e]], 1);
}

// single-workgroup full scan: deg -> rowptr/cursor (exclusive), rowptr[n]=E
__global__ __launch_bounds__(1024) void k_scan_all(const int* __restrict__ deg,
        int* __restrict__ rowptr, int* __restrict__ cursor, int n) {
    __shared__ int lds[1024];
    int t = threadIdx.x;
    int per = (n + 1023) / 1024;
    int b0 = t * per;
    int e0 = min(b0 + per, n);
    int s = 0;
    for (int i = b0; i < e0; i++) s += deg[i];
    lds[t] = s;
    __syncthreads();
    for (int o = 1; o < 1024; o <<= 1) {
        int add = (t >= o) ? lds[t - o] : 0;
        __syncthreads();
        lds[t] += add;
        __syncthreads();
    }
    int run = lds[t] - s;
    for (int i = b0; i < e0; i++) {
        int d = deg[i];
        rowptr[i] = run; cursor[i] = run; run += d;
    }
    if (t == 1023) rowptr[n] = lds[1023];
}

__global__ void k_scatter(const int* __restrict__ src, const int* __restrict__ dst,
                          const float* __restrict__ ew, int* __restrict__ cursor,
                          uint2* __restrict__ epack, int E) {
    int e = blockIdx.x * blockDim.x + threadIdx.x;
    if (e < E) {
        int p = atomicAdd(&cursor[dst[e]], 1);
        epack[p] = make_uint2((unsigned)src[e], __float_as_uint(ew[e]));
    }
}

// ---------------- merged weight prep: bf16 hi/lo B-fragment layouts ----------------
__global__ void k_wprep_all(const float* __restrict__ Wl, const float* __restrict__ Wr,
                            const float* __restrict__ encW,
                            unsigned short* __restrict__ wf_hi, unsigned short* __restrict__ wf_lo,
                            unsigned short* __restrict__ we_hi, unsigned short* __restrict__ we_lo) {
    int t = blockIdx.x * blockDim.x + threadIdx.x;
    if (t < WPREP_L) {
        int within = t % 9216, pair = t / 9216;
        int lr = pair & 1, layer = pair >> 1;
        int j = within & 7;
        int lane = (within >> 3) & 63;
        int cs = within >> 9;
        int s = cs % 3, ct = cs / 3;
        int col = ct * 16 + (lane & 15);
        int k = s * 32 + (lane >> 4) * 8 + j;
        const float* W = (lr ? Wr : Wl) + (size_t)layer * HID * HID;
        float v = W[k * HID + col];
        unsigned short hi = f32_to_bf16_rne(v);
        wf_hi[t] = hi;
        wf_lo[t] = f32_to_bf16_rne(v - bf16_to_f32(hi));
    } else if (t < WPREP_TOT) {
        int u = t - WPREP_L;
        int j = u & 7;
        int lane = (u >> 3) & 63;
        int cs = u >> 9;
        int s = cs & 3, ct = cs >> 2;
        int col = ct * 16 + (lane & 15);
        int k = s * 32 + (lane >> 4) * 8 + j;
        float v = encW[k * HID + col];
        unsigned short hi = f32_to_bf16_rne(v);
        we_hi[u] = hi;
        we_lo[u] = f32_to_bf16_rne(v - bf16_to_f32(hi));
    }
}

// ---------------- encoder via split-bf16 MFMA + fused LN/relu/split epilogue ----------------
__global__ __launch_bounds__(256) void k_enc_mfma(const float* __restrict__ x,
        const unsigned short* __restrict__ we_hi, const unsigned short* __restrict__ we_lo,
        const float* __restrict__ b,
        const float* __restrict__ lng, const float* __restrict__ lnb,
        float* __restrict__ h,
        unsigned short* __restrict__ hn_hi, unsigned short* __restrict__ hn_lo, int n) {
    int t = threadIdx.x;
    int wave = t >> 6, lane = t & 63;
    int quad = lane >> 4, lid = lane & 15;
    int r0 = blockIdx.x * 64 + wave * 16;
    int arow = r0 + lid; if (arow >= n) arow = n - 1;
    short8 aH[4], aL[4];
    #pragma unroll
    for (int s = 0; s < 4; s++) {
        float4 p0 = *(const float4*)(x + (size_t)arow * FIN + s * 32 + quad * 8);
        float4 p1 = *(const float4*)(x + (size_t)arow * FIN + s * 32 + quad * 8 + 4);
        float f[8] = {p0.x, p0.y, p0.z, p0.w, p1.x, p1.y, p1.z, p1.w};
        #pragma unroll
        for (int j = 0; j < 8; j++) {
            unsigned short hi = f32_to_bf16_rne(f[j]);
            aH[s][j] = (short)hi;
            aL[s][j] = (short)f32_to_bf16_rne(f[j] - bf16_to_f32(hi));
        }
    }
    floatx4 o[6];
    #pragma unroll
    for (int ct = 0; ct < 6; ct++) {
        floatx4 acc = {0.f, 0.f, 0.f, 0.f};
        #pragma unroll
        for (int s = 0; s < 4; s++) {
            short8 bH = *(const short8*)(we_hi + ((ct * 4 + s) * 64 + lane) * 8);
            short8 bL = *(const short8*)(we_lo + ((ct * 4 + s) * 64 + lane) * 8);
            acc = __builtin_amdgcn_mfma_f32_16x16x32_bf16(aH[s], bH, acc, 0, 0, 0);
            acc = __builtin_amdgcn_mfma_f32_16x16x32_bf16(aH[s], bL, acc, 0, 0, 0);
            acc = __builtin_amdgcn_mfma_f32_16x16x32_bf16(aL[s], bH, acc, 0, 0, 0);
        }
        float bv = b[ct * 16 + lid];
        #pragma unroll
        for (int rg = 0; rg < 4; rg++) o[ct][rg] = acc[rg] + bv;
    }
    #pragma unroll
    for (int rg = 0; rg < 4; rg++) {
        float s1 = 0.f, s2 = 0.f;
        #pragma unroll
        for (int ct = 0; ct < 6; ct++) { s1 += o[ct][rg]; s2 += o[ct][rg] * o[ct][rg]; }
        #pragma unroll
        for (int off = 1; off < 16; off <<= 1) {
            s1 += __shfl_xor(s1, off);
            s2 += __shfl_xor(s2, off);
        }
        float mu = s1 * (1.f / 96.f);
        float var = s2 * (1.f / 96.f) - mu * mu;
        float rs = rsqrtf(var + 1e-5f);
        int orow = r0 + quad * 4 + rg;
        if (orow < n) {
            #pragma unroll
            for (int ct = 0; ct < 6; ct++) {
                int col = ct * 16 + lid;
                float v = o[ct][rg];
                h[(size_t)orow * HID + col] = v;
                float y = fmaxf((v - mu) * rs * lng[col] + lnb[col], 0.f);
                unsigned short hi = f32_to_bf16_rne(y);
                hn_hi[(size_t)orow * HID + col] = hi;
                hn_lo[(size_t)orow * HID + col] = f32_to_bf16_rne(y - bf16_to_f32(hi));
            }
        }
    }
}

// ---------------- layer GEMMs via split-bf16 MFMA, B-frags direct from global (L2-hot) ----------------
__global__ __launch_bounds__(256) void k_gemm2_mfma(
        const unsigned short* __restrict__ hn_hi, const unsigned short* __restrict__ hn_lo,
        const unsigned short* __restrict__ wf_hi, const unsigned short* __restrict__ wf_lo,
        const float* __restrict__ bl, const float* __restrict__ br,
        unsigned short* __restrict__ xl_h, unsigned short* __restrict__ xr_h, int n) {
    int t = threadIdx.x;
    int wave = t >> 6, lane = t & 63;
    int quad = lane >> 4, lid = lane & 15;
    int r0 = blockIdx.x * 64 + wave * 16;
    int arow = r0 + lid; if (arow >= n) arow = n - 1;
    short8 aH[3], aL[3];
    #pragma unroll
    for (int s = 0; s < 3; s++) {
        aH[s] = *(const short8*)(hn_hi + (size_t)arow * HID + s * 32 + quad * 8);
        aL[s] = *(const short8*)(hn_lo + (size_t)arow * HID + s * 32 + quad * 8);
    }
    #pragma unroll
    for (int lr = 0; lr < 2; lr++) {
        const unsigned short* sh = wf_hi + lr * 9216;
        const unsigned short* sl = wf_lo + lr * 9216;
        const float* bias = lr ? br : bl;
        unsigned short* out = lr ? xr_h : xl_h;
        #pragma unroll
        for (int ct = 0; ct < 6; ct++) {
            floatx4 acc = {0.f, 0.f, 0.f, 0.f};
            #pragma unroll
            for (int s = 0; s < 3; s++) {
                short8 bH = *(const short8*)(sh + ((ct * 3 + s) * 64 + lane) * 8);
                short8 bL = *(const short8*)(sl + ((ct * 3 + s) * 64 + lane) * 8);
                acc = __builtin_amdgcn_mfma_f32_16x16x32_bf16(aH[s], bH, acc, 0, 0, 0);
                acc = __builtin_amdgcn_mfma_f32_16x16x32_bf16(aH[s], bL, acc, 0, 0, 0);
                acc = __builtin_amdgcn_mfma_f32_16x16x32_bf16(aL[s], bH, acc, 0, 0, 0);
            }
            int col = ct * 16 + lid;
            float bv = bias[col];
            #pragma unroll
            for (int rg = 0; rg < 4; rg++) {
                int orow = r0 + quad * 4 + rg;
                if (orow < n) {
                    _Float16 hv = (_Float16)(acc[rg] + bv);
                    out[(size_t)orow * HID + col] = *(unsigned short*)&hv;
                }
            }
        }
    }
}

// ---------------- fused GATv2 + residual + next-layer LN (or final LN+fc) ----------------
__global__ __launch_bounds__(256) void k_gat_fused(
        const unsigned short* __restrict__ xl_h, const unsigned short* __restrict__ xr_h,
        const uint2* __restrict__ ep, const int* __restrict__ rowptr,
        const float* __restrict__ We, const float* __restrict__ att, const float* __restrict__ bias,
        float* __restrict__ h,
        unsigned short* __restrict__ hn_hi, unsigned short* __restrict__ hn_lo,
        float* __restrict__ out_final,
        const float* __restrict__ g, const float* __restrict__ bt,
        const float* __restrict__ fcW, const float* __restrict__ fcb,
        int mode, int n) {
    int lane = threadIdx.x & 63;
    int node = blockIdx.x * 4 + (threadIdx.x >> 6);
    if (node >= n) return;
    int grp = lane >> 4, sub = lane & 15;
    bool act = sub < 12;
    int d0 = sub * 8;
    unsigned gOffB = (unsigned)((act ? sub : 11) * 16);

    const float LOG2E = 1.4426950408889634f;
    half2v we_h[4], at_h[4], xr_hv[4];
    {
        union U8i { uint4 u; half2v h2[4]; };
        U8i xrw;
        xrw.u = *(const uint4*)((const char*)xr_h + ((unsigned)node * 192u + gOffB));
        if (act) {
            float4 a0 = *(const float4*)(We + d0),  a1 = *(const float4*)(We + d0 + 4);
            float4 c0 = *(const float4*)(att + d0), c1 = *(const float4*)(att + d0 + 4);
            we_h[0] = half2v{(_Float16)a0.x, (_Float16)a0.y}; we_h[1] = half2v{(_Float16)a0.z, (_Float16)a0.w};
            we_h[2] = half2v{(_Float16)a1.x, (_Float16)a1.y}; we_h[3] = half2v{(_Float16)a1.z, (_Float16)a1.w};
            at_h[0] = half2v{(_Float16)(c0.x*LOG2E), (_Float16)(c0.y*LOG2E)};
            at_h[1] = half2v{(_Float16)(c0.z*LOG2E), (_Float16)(c0.w*LOG2E)};
            at_h[2] = half2v{(_Float16)(c1.x*LOG2E), (_Float16)(c1.y*LOG2E)};
            at_h[3] = half2v{(_Float16)(c1.z*LOG2E), (_Float16)(c1.w*LOG2E)};
            #pragma unroll
            for (int j = 0; j < 4; j++) xr_hv[j] = xrw.h2[j];
        } else {
            #pragma unroll
            for (int j = 0; j < 4; j++) {
                we_h[j] = half2v{(_Float16)0.f, (_Float16)0.f};
                at_h[j] = we_h[j]; xr_hv[j] = we_h[j];
            }
        }
    }
    const half2v c02 = half2v{(_Float16)0.2f, (_Float16)0.2f};

    int beg = rowptr[node], end = rowptr[node + 1];
    float ssum = 0.f;
    float acc[8];
    #pragma unroll
    for (int j = 0; j < 8; j++) acc[j] = 0.f;

    union U8 { uint4 u; half2v h2[4]; _Float16 hf[8]; };

    auto lq = [&](int p, uint4& vraw, float& w, bool& val) {
        int pe = p + grp;
        val = pe < end;
        int pc = val ? pe : end - 1;
        uint2 e = ep[pc];
        w = __uint_as_float(e.y);
        vraw = *(const uint4*)((const char*)xl_h + (e.x * 192u + gOffB));
    };
    auto proc = [&](const uint4& vraw, float w, bool val) {
        U8 cv; cv.u = vraw;
        _Float16 wh = (_Float16)w;
        half2v w2 = half2v{wh, wh};
        float q = 0.f;
        #pragma unroll
        for (int j = 0; j < 4; j++) {
            half2v t = cv.h2[j] + xr_hv[j];
            t = w2 * we_h[j] + t;
            half2v t2 = t * c02;
            t = __builtin_elementwise_max(t, t2);
#if __has_builtin(__builtin_amdgcn_fdot2)
            q = __builtin_amdgcn_fdot2(t, at_h[j], q, false);
#else
            q = fmaf((float)t[0], (float)at_h[j][0], q);
            q = fmaf((float)t[1], (float)at_h[j][1], q);
#endif
        }
        q += __shfl_xor(q, 1); q += __shfl_xor(q, 2);
        q += __shfl_xor(q, 4); q += __shfl_xor(q, 8);
        float e = val ? exp2f(q) : 0.f;
        ssum += e;
        #pragma unroll
        for (int j = 0; j < 8; j++) acc[j] = fmaf((float)cv.hf[j], e, acc[j]);
    };

    if (beg < end) {
        uint4 vA, vB; float wA, wB; bool okA, okB;
        lq(beg,     vA, wA, okA);
        lq(beg + 4, vB, wB, okB);
        for (int p = beg; p < end; p += 8) {
            proc(vA, wA, okA);
            lq(p + 8, vA, wA, okA);
            proc(vB, wB, okB);
            lq(p + 12, vB, wB, okB);
        }
    }

    ssum += __shfl_xor(ssum, 16); ssum += __shfl_xor(ssum, 32);
    #pragma unroll
    for (int j = 0; j < 8; j++) {
        acc[j] += __shfl_xor(acc[j], 16);
        acc[j] += __shfl_xor(acc[j], 32);
    }
    float inv = 1.f / (ssum + 1e-16f);

    float nh[8];
    float s1 = 0.f, s2 = 0.f;
    if (act) {
        float4 h0 = *(const float4*)(h + (size_t)node * HID + d0);
        float4 h1 = *(const float4*)(h + (size_t)node * HID + d0 + 4);
        float4 b0 = *(const float4*)(bias + d0);
        float4 b1 = *(const float4*)(bias + d0 + 4);
        float hv[8] = {h0.x,h0.y,h0.z,h0.w,h1.x,h1.y,h1.z,h1.w};
        float bv[8] = {b0.x,b0.y,b0.z,b0.w,b1.x,b1.y,b1.z,b1.w};
        #pragma unroll
        for (int j = 0; j < 8; j++) {
            nh[j] = hv[j] + acc[j] * inv + bv[j];
            s1 += nh[j];
            s2 += nh[j] * nh[j];
        }
    } else {
        #pragma unroll
        for (int j = 0; j < 8; j++) nh[j] = 0.f;
    }
    #pragma unroll
    for (int off = 1; off < 16; off <<= 1) {
        s1 += __shfl_xor(s1, off);
        s2 += __shfl_xor(s2, off);
    }
    float mu = s1 * (1.f / 96.f);
    float var = s2 * (1.f / 96.f) - mu * mu;
    float rs = rsqrtf(var + 1e-5f);

    if (mode == 0) {
        if (grp == 0 && act) {
            float4 g0 = *(const float4*)(g + d0),  g1 = *(const float4*)(g + d0 + 4);
            float4 t0 = *(const float4*)(bt + d0), t1 = *(const float4*)(bt + d0 + 4);
            float gv[8] = {g0.x,g0.y,g0.z,g0.w,g1.x,g1.y,g1.z,g1.w};
            float tv[8] = {t0.x,t0.y,t0.z,t0.w,t1.x,t1.y,t1.z,t1.w};
            *(float4*)(h + (size_t)node * HID + d0)     = make_float4(nh[0], nh[1], nh[2], nh[3]);
            *(float4*)(h + (size_t)node * HID + d0 + 4) = make_float4(nh[4], nh[5], nh[6], nh[7]);
            unsigned hi[4], lo[4];
            #pragma unroll
            for (int j = 0; j < 4; j++) {
                float ox = fmaxf((nh[2*j]   - mu) * rs * gv[2*j]   + tv[2*j],   0.f);
                float oy = fmaxf((nh[2*j+1] - mu) * rs * gv[2*j+1] + tv[2*j+1], 0.f);
                unsigned short hx = f32_to_bf16_rne(ox), hy = f32_to_bf16_rne(oy);
                unsigned short lx = f32_to_bf16_rne(ox - bf16_to_f32(hx));
                unsigned short ly = f32_to_bf16_rne(oy - bf16_to_f32(hy));
                hi[j] = (unsigned)hx | ((unsigned)hy << 16);
                lo[j] = (unsigned)lx | ((unsigned)ly << 16);
            }
            *(uint4*)(hn_hi + (size_t)node * HID + d0) = make_uint4(hi[0], hi[1], hi[2], hi[3]);
            *(uint4*)(hn_lo + (size_t)node * HID + d0) = make_uint4(lo[0], lo[1], lo[2], lo[3]);
        }
    } else {
        float pacc = 0.f;
        if (act) {
            float4 g0 = *(const float4*)(g + d0),  g1 = *(const float4*)(g + d0 + 4);
            float4 t0 = *(const float4*)(bt + d0), t1 = *(const float4*)(bt + d0 + 4);
            float4 w0 = *(const float4*)(fcW + d0), w1 = *(const float4*)(fcW + d0 + 4);
            float gv[8] = {g0.x,g0.y,g0.z,g0.w,g1.x,g1.y,g1.z,g1.w};
            float tv[8] = {t0.x,t0.y,t0.z,t0.w,t1.x,t1.y,t1.z,t1.w};
            float wv[8] = {w0.x,w0.y,w0.z,w0.w,w1.x,w1.y,w1.z,w1.w};
            #pragma unroll
            for (int j = 0; j < 8; j++) {
                float y = fmaxf((nh[j] - mu) * rs * gv[j] + tv[j], 0.f);
                pacc = fmaf(y, wv[j], pacc);
            }
        }
        #pragma unroll
        for (int off = 1; off < 16; off <<= 1) pacc += __shfl_xor(pacc, off);
        if (lane == 0) out_final[node] = pacc + fcb[0];
    }
}

extern "C" void kernel_launch(void* const* d_in, const int* in_sizes, int n_in,
                              void* d_out, int out_size, void* d_ws, size_t ws_size,
                              hipStream_t stream) {
    const float* x    = (const float*)d_in[0];
    const int*   ei   = (const int*)  d_in[1];
    const float* ew   = (const float*)d_in[2];
    const float* encW = (const float*)d_in[3];
    const float* encB = (const float*)d_in[4];
    const float* Wl   = (const float*)d_in[5];
    const float* bl   = (const float*)d_in[6];
    const float* Wr   = (const float*)d_in[7];
    const float* br   = (const float*)d_in[8];
    const float* We   = (const float*)d_in[9];
    const float* att  = (const float*)d_in[10];
    const float* bias = (const float*)d_in[11];
    const float* lng  = (const float*)d_in[12];
    const float* lnb  = (const float*)d_in[13];
    const float* lnfg = (const float*)d_in[14];
    const float* lnfb = (const float*)d_in[15];
    const float* fcW  = (const float*)d_in[16];
    const float* fcb  = (const float*)d_in[17];
    float* out = (float*)d_out;

    const int* src = ei;
    const int* dst = ei + EE;

    char* ws = (char*)d_ws;
    size_t off = 0;
    auto alloc = [&](size_t bytes) -> void* {
        void* p = ws + off;
        off += (bytes + 255) & ~(size_t)255;
        return p;
    };
    float* h      = (float*)alloc((size_t)NN * HID * 4);
    unsigned short* xl_h  = (unsigned short*)alloc((size_t)NN * HID * 2 + 256);
    unsigned short* xr_h  = (unsigned short*)alloc((size_t)NN * HID * 2 + 256);
    unsigned short* hn_hi = (unsigned short*)alloc((size_t)NN * HID * 2);
    unsigned short* hn_lo = (unsigned short*)alloc((size_t)NN * HID * 2);
    unsigned short* wf_hi = (unsigned short*)alloc((size_t)WPREP_L * 2);
    unsigned short* wf_lo = (unsigned short*)alloc((size_t)WPREP_L * 2);
    unsigned short* we_hi = (unsigned short*)alloc(12288 * 2);
    unsigned short* we_lo = (unsigned short*)alloc(12288 * 2);
    int*   deg    = (int*)  alloc((size_t)NN * 4);
    int*   rowptr = (int*)  alloc((size_t)(NN + 1) * 4);
    int*   cursor = (int*)  alloc((size_t)NN * 4);
    uint2* epack  = (uint2*)alloc((size_t)EE * 8);

    const int EB = (EE + 255) / 256;           // 3125
    const int MB = (NN + 63) / 64;             // 782
    const int WB = (NN + 3) / 4;               // 12500

    // CSR build
    hipMemsetAsync(deg, 0, (size_t)NN * 4, stream);
    k_hist<<<EB, 256, 0, stream>>>(dst, deg, EE);
    k_scan_all<<<1, 1024, 0, stream>>>(deg, rowptr, cursor, NN);
    k_scatter<<<EB, 256, 0, stream>>>(src, dst, ew, cursor, epack, EE);

    // weight prep (layers + encoder, one kernel)
    k_wprep_all<<<(WPREP_TOT + 255) / 256, 256, 0, stream>>>(Wl, Wr, encW, wf_hi, wf_lo, we_hi, we_lo);

    // encoder (+fused first LN)
    k_enc_mfma<<<MB, 256, 0, stream>>>(x, we_hi, we_lo, encB, lng, lnb, h, hn_hi, hn_lo, NN);

    for (int l = 0; l < NL; l++) {
        k_gemm2_mfma<<<MB, 256, 0, stream>>>(hn_hi, hn_lo,
            wf_hi + (size_t)l * 2 * 9216, wf_lo + (size_t)l * 2 * 9216,
            bl + l * HID, br + l * HID, xl_h, xr_h, NN);
        if (l < NL - 1) {
            k_gat_fused<<<WB, 256, 0, stream>>>(xl_h, xr_h, epack, rowptr,
                We + l * HID, att + l * HID, bias + l * HID,
                h, hn_hi, hn_lo, (float*)nullptr,
                lng + (l + 1) * HID, lnb + (l + 1) * HID,
                (const float*)nullptr, (const float*)nullptr, 0, NN);
        } else {
            k_gat_fused<<<WB, 256, 0, stream>>>(xl_h, xr_h, epack, rowptr,
                We + l * HID, att + l * HID, bias + l * HID,
                h, (unsigned short*)nullptr, (unsigned short*)nullptr, out,
                lnfg, lnfb, fcW, fcb, 1, NN);
        }
    }
}

// Round 11
// 509.490 us; speedup vs baseline: 1.1808x; 1.1808x over previous
//
#include <hip/hip_runtime.h>
#include <math.h>

#define NN 50000
#define EE 800000
#define FIN 128
#define HID 96
#define NL 4
#define CHUNK 1024

typedef __attribute__((ext_vector_type(8))) short short8;
typedef __attribute__((ext_vector_type(4))) float floatx4;
typedef __attribute__((ext_vector_type(2))) _Float16 half2v;

#define WPREP_L (NL * 2 * 9216)       // 73728
#define WPREP_TOT (WPREP_L + 12288)   // 86016

__device__ __forceinline__ unsigned short f32_to_bf16_rne(float x) {
    unsigned u = __float_as_uint(x);
    unsigned r = (u + 0x7FFFu + ((u >> 16) & 1u)) >> 16;
    return (unsigned short)r;
}
__device__ __forceinline__ float bf16_to_f32(unsigned short h) {
    return __uint_as_float(((unsigned)h) << 16);
}

// ---------------- CSR build (multi-block scan: ~5 us total) ----------------
__global__ void k_hist(const int* __restrict__ dst, int* __restrict__ deg, int E) {
    int e = blockIdx.x * blockDim.x + threadIdx.x;
    if (e < E) atomicAdd(&deg[dst[e]], 1);
}

__global__ void k_scan1(const int* __restrict__ deg, int* __restrict__ partials, int n) {
    __shared__ int lds[256];
    int t = threadIdx.x;
    int base = blockIdx.x * CHUNK + t * 4;
    int s = 0;
    #pragma unroll
    for (int q = 0; q < 4; q++) { int idx = base + q; if (idx < n) s += deg[idx]; }
    lds[t] = s; __syncthreads();
    for (int o = 128; o > 0; o >>= 1) { if (t < o) lds[t] += lds[t + o]; __syncthreads(); }
    if (t == 0) partials[blockIdx.x] = lds[0];
}

__global__ void k_scan_mid(int* partials, int nb, int* rowptr, int n) {
    int lane = threadIdx.x;
    int orig = (lane < nb) ? partials[lane] : 0;
    int v = orig;
    #pragma unroll
    for (int off = 1; off < 64; off <<= 1) {
        int u = __shfl_up(v, off);
        if (lane >= off) v += u;
    }
    if (lane < nb) partials[lane] = v - orig;
    if (lane == 63) rowptr[n] = v;
}

__global__ void k_scan3(const int* __restrict__ deg, const int* __restrict__ partials,
                        int* __restrict__ rowptr, int* __restrict__ cursor, int n) {
    __shared__ int lds[256];
    int t = threadIdx.x;
    int base = blockIdx.x * CHUNK + t * 4;
    int v[4];
    #pragma unroll
    for (int q = 0; q < 4; q++) { int idx = base + q; v[q] = (idx < n) ? deg[idx] : 0; }
    int tsum = v[0] + v[1] + v[2] + v[3];
    lds[t] = tsum; __syncthreads();
    for (int o = 1; o < 256; o <<= 1) {
        int add = (t >= o) ? lds[t - o] : 0;
        __syncthreads();
        lds[t] += add;
        __syncthreads();
    }
    int excl = lds[t] - tsum;
    int run = partials[blockIdx.x] + excl;
    #pragma unroll
    for (int q = 0; q < 4; q++) {
        int idx = base + q;
        if (idx < n) { rowptr[idx] = run; cursor[idx] = run; run += v[q]; }
    }
}

__global__ void k_scatter(const int* __restrict__ src, const int* __restrict__ dst,
                          const float* __restrict__ ew, int* __restrict__ cursor,
                          uint2* __restrict__ epack, int E) {
    int e = blockIdx.x * blockDim.x + threadIdx.x;
    if (e < E) {
        int p = atomicAdd(&cursor[dst[e]], 1);
        epack[p] = make_uint2((unsigned)src[e], __float_as_uint(ew[e]));
    }
}

// ---------------- merged weight prep: bf16 hi/lo B-fragment layouts ----------------
__global__ void k_wprep_all(const float* __restrict__ Wl, const float* __restrict__ Wr,
                            const float* __restrict__ encW,
                            unsigned short* __restrict__ wf_hi, unsigned short* __restrict__ wf_lo,
                            unsigned short* __restrict__ we_hi, unsigned short* __restrict__ we_lo) {
    int t = blockIdx.x * blockDim.x + threadIdx.x;
    if (t < WPREP_L) {
        int within = t % 9216, pair = t / 9216;
        int lr = pair & 1, layer = pair >> 1;
        int j = within & 7;
        int lane = (within >> 3) & 63;
        int cs = within >> 9;
        int s = cs % 3, ct = cs / 3;
        int col = ct * 16 + (lane & 15);
        int k = s * 32 + (lane >> 4) * 8 + j;
        const float* W = (lr ? Wr : Wl) + (size_t)layer * HID * HID;
        float v = W[k * HID + col];
        unsigned short hi = f32_to_bf16_rne(v);
        wf_hi[t] = hi;
        wf_lo[t] = f32_to_bf16_rne(v - bf16_to_f32(hi));
    } else if (t < WPREP_TOT) {
        int u = t - WPREP_L;
        int j = u & 7;
        int lane = (u >> 3) & 63;
        int cs = u >> 9;
        int s = cs & 3, ct = cs >> 2;
        int col = ct * 16 + (lane & 15);
        int k = s * 32 + (lane >> 4) * 8 + j;
        float v = encW[k * HID + col];
        unsigned short hi = f32_to_bf16_rne(v);
        we_hi[u] = hi;
        we_lo[u] = f32_to_bf16_rne(v - bf16_to_f32(hi));
    }
}

// ---------------- encoder via split-bf16 MFMA + fused LN/relu/split epilogue ----------------
__global__ __launch_bounds__(256) void k_enc_mfma(const float* __restrict__ x,
        const unsigned short* __restrict__ we_hi, const unsigned short* __restrict__ we_lo,
        const float* __restrict__ b,
        const float* __restrict__ lng, const float* __restrict__ lnb,
        float* __restrict__ h,
        unsigned short* __restrict__ hn_hi, unsigned short* __restrict__ hn_lo, int n) {
    int t = threadIdx.x;
    int wave = t >> 6, lane = t & 63;
    int quad = lane >> 4, lid = lane & 15;
    int r0 = blockIdx.x * 64 + wave * 16;
    int arow = r0 + lid; if (arow >= n) arow = n - 1;
    short8 aH[4], aL[4];
    #pragma unroll
    for (int s = 0; s < 4; s++) {
        float4 p0 = *(const float4*)(x + (size_t)arow * FIN + s * 32 + quad * 8);
        float4 p1 = *(const float4*)(x + (size_t)arow * FIN + s * 32 + quad * 8 + 4);
        float f[8] = {p0.x, p0.y, p0.z, p0.w, p1.x, p1.y, p1.z, p1.w};
        #pragma unroll
        for (int j = 0; j < 8; j++) {
            unsigned short hi = f32_to_bf16_rne(f[j]);
            aH[s][j] = (short)hi;
            aL[s][j] = (short)f32_to_bf16_rne(f[j] - bf16_to_f32(hi));
        }
    }
    floatx4 o[6];
    #pragma unroll
    for (int ct = 0; ct < 6; ct++) {
        floatx4 acc = {0.f, 0.f, 0.f, 0.f};
        #pragma unroll
        for (int s = 0; s < 4; s++) {
            short8 bH = *(const short8*)(we_hi + ((ct * 4 + s) * 64 + lane) * 8);
            short8 bL = *(const short8*)(we_lo + ((ct * 4 + s) * 64 + lane) * 8);
            acc = __builtin_amdgcn_mfma_f32_16x16x32_bf16(aH[s], bH, acc, 0, 0, 0);
            acc = __builtin_amdgcn_mfma_f32_16x16x32_bf16(aH[s], bL, acc, 0, 0, 0);
            acc = __builtin_amdgcn_mfma_f32_16x16x32_bf16(aL[s], bH, acc, 0, 0, 0);
        }
        float bv = b[ct * 16 + lid];
        #pragma unroll
        for (int rg = 0; rg < 4; rg++) o[ct][rg] = acc[rg] + bv;
    }
    #pragma unroll
    for (int rg = 0; rg < 4; rg++) {
        float s1 = 0.f, s2 = 0.f;
        #pragma unroll
        for (int ct = 0; ct < 6; ct++) { s1 += o[ct][rg]; s2 += o[ct][rg] * o[ct][rg]; }
        #pragma unroll
        for (int off = 1; off < 16; off <<= 1) {
            s1 += __shfl_xor(s1, off);
            s2 += __shfl_xor(s2, off);
        }
        float mu = s1 * (1.f / 96.f);
        float var = s2 * (1.f / 96.f) - mu * mu;
        float rs = rsqrtf(var + 1e-5f);
        int orow = r0 + quad * 4 + rg;
        if (orow < n) {
            #pragma unroll
            for (int ct = 0; ct < 6; ct++) {
                int col = ct * 16 + lid;
                float v = o[ct][rg];
                h[(size_t)orow * HID + col] = v;
                float y = fmaxf((v - mu) * rs * lng[col] + lnb[col], 0.f);
                unsigned short hi = f32_to_bf16_rne(y);
                hn_hi[(size_t)orow * HID + col] = hi;
                hn_lo[(size_t)orow * HID + col] = f32_to_bf16_rne(y - bf16_to_f32(hi));
            }
        }
    }
}

// ---------------- layer GEMMs via split-bf16 MFMA, B-frags direct from global (L2-hot) ----------------
__global__ __launch_bounds__(256) void k_gemm2_mfma(
        const unsigned short* __restrict__ hn_hi, const unsigned short* __restrict__ hn_lo,
        const unsigned short* __restrict__ wf_hi, const unsigned short* __restrict__ wf_lo,
        const float* __restrict__ bl, const float* __restrict__ br,
        unsigned short* __restrict__ xl_h, unsigned short* __restrict__ xr_h, int n) {
    int t = threadIdx.x;
    int wave = t >> 6, lane = t & 63;
    int quad = lane >> 4, lid = lane & 15;
    int r0 = blockIdx.x * 64 + wave * 16;
    int arow = r0 + lid; if (arow >= n) arow = n - 1;
    short8 aH[3], aL[3];
    #pragma unroll
    for (int s = 0; s < 3; s++) {
        aH[s] = *(const short8*)(hn_hi + (size_t)arow * HID + s * 32 + quad * 8);
        aL[s] = *(const short8*)(hn_lo + (size_t)arow * HID + s * 32 + quad * 8);
    }
    #pragma unroll
    for (int lr = 0; lr < 2; lr++) {
        const unsigned short* sh = wf_hi + lr * 9216;
        const unsigned short* sl = wf_lo + lr * 9216;
        const float* bias = lr ? br : bl;
        unsigned short* out = lr ? xr_h : xl_h;
        #pragma unroll
        for (int ct = 0; ct < 6; ct++) {
            floatx4 acc = {0.f, 0.f, 0.f, 0.f};
            #pragma unroll
            for (int s = 0; s < 3; s++) {
                short8 bH = *(const short8*)(sh + ((ct * 3 + s) * 64 + lane) * 8);
                short8 bL = *(const short8*)(sl + ((ct * 3 + s) * 64 + lane) * 8);
                acc = __builtin_amdgcn_mfma_f32_16x16x32_bf16(aH[s], bH, acc, 0, 0, 0);
                acc = __builtin_amdgcn_mfma_f32_16x16x32_bf16(aH[s], bL, acc, 0, 0, 0);
                acc = __builtin_amdgcn_mfma_f32_16x16x32_bf16(aL[s], bH, acc, 0, 0, 0);
            }
            int col = ct * 16 + lid;
            float bv = bias[col];
            #pragma unroll
            for (int rg = 0; rg < 4; rg++) {
                int orow = r0 + quad * 4 + rg;
                if (orow < n) {
                    _Float16 hv = (_Float16)(acc[rg] + bv);
                    out[(size_t)orow * HID + col] = *(unsigned short*)&hv;
                }
            }
        }
    }
}

// ---------------- fused GATv2 + residual + next-layer LN (or final LN+fc) ----------------
__global__ __launch_bounds__(256) void k_gat_fused(
        const unsigned short* __restrict__ xl_h, const unsigned short* __restrict__ xr_h,
        const uint2* __restrict__ ep, const int* __restrict__ rowptr,
        const float* __restrict__ We, const float* __restrict__ att, const float* __restrict__ bias,
        float* __restrict__ h,
        unsigned short* __restrict__ hn_hi, unsigned short* __restrict__ hn_lo,
        float* __restrict__ out_final,
        const float* __restrict__ g, const float* __restrict__ bt,
        const float* __restrict__ fcW, const float* __restrict__ fcb,
        int mode, int n) {
    int lane = threadIdx.x & 63;
    int node = blockIdx.x * 4 + (threadIdx.x >> 6);
    if (node >= n) return;
    int grp = lane >> 4, sub = lane & 15;
    bool act = sub < 12;
    int d0 = sub * 8;
    unsigned gOffB = (unsigned)((act ? sub : 11) * 16);

    const float LOG2E = 1.4426950408889634f;
    half2v we_h[4], at_h[4], xr_hv[4];
    {
        union U8i { uint4 u; half2v h2[4]; };
        U8i xrw;
        xrw.u = *(const uint4*)((const char*)xr_h + ((unsigned)node * 192u + gOffB));
        if (act) {
            float4 a0 = *(const float4*)(We + d0),  a1 = *(const float4*)(We + d0 + 4);
            float4 c0 = *(const float4*)(att + d0), c1 = *(const float4*)(att + d0 + 4);
            we_h[0] = half2v{(_Float16)a0.x, (_Float16)a0.y}; we_h[1] = half2v{(_Float16)a0.z, (_Float16)a0.w};
            we_h[2] = half2v{(_Float16)a1.x, (_Float16)a1.y}; we_h[3] = half2v{(_Float16)a1.z, (_Float16)a1.w};
            at_h[0] = half2v{(_Float16)(c0.x*LOG2E), (_Float16)(c0.y*LOG2E)};
            at_h[1] = half2v{(_Float16)(c0.z*LOG2E), (_Float16)(c0.w*LOG2E)};
            at_h[2] = half2v{(_Float16)(c1.x*LOG2E), (_Float16)(c1.y*LOG2E)};
            at_h[3] = half2v{(_Float16)(c1.z*LOG2E), (_Float16)(c1.w*LOG2E)};
            #pragma unroll
            for (int j = 0; j < 4; j++) xr_hv[j] = xrw.h2[j];
        } else {
            #pragma unroll
            for (int j = 0; j < 4; j++) {
                we_h[j] = half2v{(_Float16)0.f, (_Float16)0.f};
                at_h[j] = we_h[j]; xr_hv[j] = we_h[j];
            }
        }
    }
    const half2v c02 = half2v{(_Float16)0.2f, (_Float16)0.2f};

    int beg = rowptr[node], end = rowptr[node + 1];
    float ssum = 0.f;
    float acc[8];
    #pragma unroll
    for (int j = 0; j < 8; j++) acc[j] = 0.f;

    union U8 { uint4 u; half2v h2[4]; _Float16 hf[8]; };

    auto lq = [&](int p, uint4& vraw, float& w, bool& val) {
        int pe = p + grp;
        val = pe < end;
        int pc = val ? pe : end - 1;
        uint2 e = ep[pc];
        w = __uint_as_float(e.y);
        vraw = *(const uint4*)((const char*)xl_h + (e.x * 192u + gOffB));
    };
    auto proc = [&](const uint4& vraw, float w, bool val) {
        U8 cv; cv.u = vraw;
        _Float16 wh = (_Float16)w;
        half2v w2 = half2v{wh, wh};
        float q = 0.f;
        #pragma unroll
        for (int j = 0; j < 4; j++) {
            half2v t = cv.h2[j] + xr_hv[j];
            t = w2 * we_h[j] + t;
            half2v t2 = t * c02;
            t = __builtin_elementwise_max(t, t2);
#if __has_builtin(__builtin_amdgcn_fdot2)
            q = __builtin_amdgcn_fdot2(t, at_h[j], q, false);
#else
            q = fmaf((float)t[0], (float)at_h[j][0], q);
            q = fmaf((float)t[1], (float)at_h[j][1], q);
#endif
        }
        q += __shfl_xor(q, 1); q += __shfl_xor(q, 2);
        q += __shfl_xor(q, 4); q += __shfl_xor(q, 8);
        float e = val ? exp2f(q) : 0.f;
        ssum += e;
        #pragma unroll
        for (int j = 0; j < 8; j++) acc[j] = fmaf((float)cv.hf[j], e, acc[j]);
    };

    if (beg < end) {
        uint4 vA, vB; float wA, wB; bool okA, okB;
        lq(beg,     vA, wA, okA);
        lq(beg + 4, vB, wB, okB);
        for (int p = beg; p < end; p += 8) {
            proc(vA, wA, okA);
            lq(p + 8, vA, wA, okA);
            proc(vB, wB, okB);
            lq(p + 12, vB, wB, okB);
        }
    }

    ssum += __shfl_xor(ssum, 16); ssum += __shfl_xor(ssum, 32);
    #pragma unroll
    for (int j = 0; j < 8; j++) {
        acc[j] += __shfl_xor(acc[j], 16);
        acc[j] += __shfl_xor(acc[j], 32);
    }
    float inv = 1.f / (ssum + 1e-16f);

    float nh[8];
    float s1 = 0.f, s2 = 0.f;
    if (act) {
        float4 h0 = *(const float4*)(h + (size_t)node * HID + d0);
        float4 h1 = *(const float4*)(h + (size_t)node * HID + d0 + 4);
        float4 b0 = *(const float4*)(bias + d0);
        float4 b1 = *(const float4*)(bias + d0 + 4);
        float hv[8] = {h0.x,h0.y,h0.z,h0.w,h1.x,h1.y,h1.z,h1.w};
        float bv[8] = {b0.x,b0.y,b0.z,b0.w,b1.x,b1.y,b1.z,b1.w};
        #pragma unroll
        for (int j = 0; j < 8; j++) {
            nh[j] = hv[j] + acc[j] * inv + bv[j];
            s1 += nh[j];
            s2 += nh[j] * nh[j];
        }
    } else {
        #pragma unroll
        for (int j = 0; j < 8; j++) nh[j] = 0.f;
    }
    #pragma unroll
    for (int off = 1; off < 16; off <<= 1) {
        s1 += __shfl_xor(s1, off);
        s2 += __shfl_xor(s2, off);
    }
    float mu = s1 * (1.f / 96.f);
    float var = s2 * (1.f / 96.f) - mu * mu;
    float rs = rsqrtf(var + 1e-5f);

    if (mode == 0) {
        if (grp == 0 && act) {
            float4 g0 = *(const float4*)(g + d0),  g1 = *(const float4*)(g + d0 + 4);
            float4 t0 = *(const float4*)(bt + d0), t1 = *(const float4*)(bt + d0 + 4);
            float gv[8] = {g0.x,g0.y,g0.z,g0.w,g1.x,g1.y,g1.z,g1.w};
            float tv[8] = {t0.x,t0.y,t0.z,t0.w,t1.x,t1.y,t1.z,t1.w};
            *(float4*)(h + (size_t)node * HID + d0)     = make_float4(nh[0], nh[1], nh[2], nh[3]);
            *(float4*)(h + (size_t)node * HID + d0 + 4) = make_float4(nh[4], nh[5], nh[6], nh[7]);
            unsigned hi[4], lo[4];
            #pragma unroll
            for (int j = 0; j < 4; j++) {
                float ox = fmaxf((nh[2*j]   - mu) * rs * gv[2*j]   + tv[2*j],   0.f);
                float oy = fmaxf((nh[2*j+1] - mu) * rs * gv[2*j+1] + tv[2*j+1], 0.f);
                unsigned short hx = f32_to_bf16_rne(ox), hy = f32_to_bf16_rne(oy);
                unsigned short lx = f32_to_bf16_rne(ox - bf16_to_f32(hx));
                unsigned short ly = f32_to_bf16_rne(oy - bf16_to_f32(hy));
                hi[j] = (unsigned)hx | ((unsigned)hy << 16);
                lo[j] = (unsigned)lx | ((unsigned)ly << 16);
            }
            *(uint4*)(hn_hi + (size_t)node * HID + d0) = make_uint4(hi[0], hi[1], hi[2], hi[3]);
            *(uint4*)(hn_lo + (size_t)node * HID + d0) = make_uint4(lo[0], lo[1], lo[2], lo[3]);
        }
    } else {
        float pacc = 0.f;
        if (act) {
            float4 g0 = *(const float4*)(g + d0),  g1 = *(const float4*)(g + d0 + 4);
            float4 t0 = *(const float4*)(bt + d0), t1 = *(const float4*)(bt + d0 + 4);
            float4 w0 = *(const float4*)(fcW + d0), w1 = *(const float4*)(fcW + d0 + 4);
            float gv[8] = {g0.x,g0.y,g0.z,g0.w,g1.x,g1.y,g1.z,g1.w};
            float tv[8] = {t0.x,t0.y,t0.z,t0.w,t1.x,t1.y,t1.z,t1.w};
            float wv[8] = {w0.x,w0.y,w0.z,w0.w,w1.x,w1.y,w1.z,w1.w};
            #pragma unroll
            for (int j = 0; j < 8; j++) {
                float y = fmaxf((nh[j] - mu) * rs * gv[j] + tv[j], 0.f);
                pacc = fmaf(y, wv[j], pacc);
            }
        }
        #pragma unroll
        for (int off = 1; off < 16; off <<= 1) pacc += __shfl_xor(pacc, off);
        if (lane == 0) out_final[node] = pacc + fcb[0];
    }
}

extern "C" void kernel_launch(void* const* d_in, const int* in_sizes, int n_in,
                              void* d_out, int out_size, void* d_ws, size_t ws_size,
                              hipStream_t stream) {
    const float* x    = (const float*)d_in[0];
    const int*   ei   = (const int*)  d_in[1];
    const float* ew   = (const float*)d_in[2];
    const float* encW = (const float*)d_in[3];
    const float* encB = (const float*)d_in[4];
    const float* Wl   = (const float*)d_in[5];
    const float* bl   = (const float*)d_in[6];
    const float* Wr   = (const float*)d_in[7];
    const float* br   = (const float*)d_in[8];
    const float* We   = (const float*)d_in[9];
    const float* att  = (const float*)d_in[10];
    const float* bias = (const float*)d_in[11];
    const float* lng  = (const float*)d_in[12];
    const float* lnb  = (const float*)d_in[13];
    const float* lnfg = (const float*)d_in[14];
    const float* lnfb = (const float*)d_in[15];
    const float* fcW  = (const float*)d_in[16];
    const float* fcb  = (const float*)d_in[17];
    float* out = (float*)d_out;

    const int* src = ei;
    const int* dst = ei + EE;

    char* ws = (char*)d_ws;
    size_t off = 0;
    auto alloc = [&](size_t bytes) -> void* {
        void* p = ws + off;
        off += (bytes + 255) & ~(size_t)255;
        return p;
    };
    float* h      = (float*)alloc((size_t)NN * HID * 4);
    unsigned short* xl_h  = (unsigned short*)alloc((size_t)NN * HID * 2 + 256);
    unsigned short* xr_h  = (unsigned short*)alloc((size_t)NN * HID * 2 + 256);
    unsigned short* hn_hi = (unsigned short*)alloc((size_t)NN * HID * 2);
    unsigned short* hn_lo = (unsigned short*)alloc((size_t)NN * HID * 2);
    unsigned short* wf_hi = (unsigned short*)alloc((size_t)WPREP_L * 2);
    unsigned short* wf_lo = (unsigned short*)alloc((size_t)WPREP_L * 2);
    unsigned short* we_hi = (unsigned short*)alloc(12288 * 2);
    unsigned short* we_lo = (unsigned short*)alloc(12288 * 2);
    int*   deg    = (int*)  alloc((size_t)NN * 4);
    int*   rowptr = (int*)  alloc((size_t)(NN + 1) * 4);
    int*   cursor = (int*)  alloc((size_t)NN * 4);
    uint2* epack  = (uint2*)alloc((size_t)EE * 8);
    int*   parts  = (int*)  alloc(256 * 4);

    const int NB = (NN + CHUNK - 1) / CHUNK;   // 49
    const int EB = (EE + 255) / 256;           // 3125
    const int MB = (NN + 63) / 64;             // 782
    const int WB = (NN + 3) / 4;               // 12500

    // CSR build
    hipMemsetAsync(deg, 0, (size_t)NN * 4, stream);
    k_hist<<<EB, 256, 0, stream>>>(dst, deg, EE);
    k_scan1<<<NB, 256, 0, stream>>>(deg, parts, NN);
    k_scan_mid<<<1, 64, 0, stream>>>(parts, NB, rowptr, NN);
    k_scan3<<<NB, 256, 0, stream>>>(deg, parts, rowptr, cursor, NN);
    k_scatter<<<EB, 256, 0, stream>>>(src, dst, ew, cursor, epack, EE);

    // weight prep (layers + encoder, one kernel)
    k_wprep_all<<<(WPREP_TOT + 255) / 256, 256, 0, stream>>>(Wl, Wr, encW, wf_hi, wf_lo, we_hi, we_lo);

    // encoder (+fused first LN)
    k_enc_mfma<<<MB, 256, 0, stream>>>(x, we_hi, we_lo, encB, lng, lnb, h, hn_hi, hn_lo, NN);

    for (int l = 0; l < NL; l++) {
        k_gemm2_mfma<<<MB, 256, 0, stream>>>(hn_hi, hn_lo,
            wf_hi + (size_t)l * 2 * 9216, wf_lo + (size_t)l * 2 * 9216,
            bl + l * HID, br + l * HID, xl_h, xr_h, NN);
        if (l < NL - 1) {
            k_gat_fused<<<WB, 256, 0, stream>>>(xl_h, xr_h, epack, rowptr,
                We + l * HID, att + l * HID, bias + l * HID,
                h, hn_hi, hn_lo, (float*)nullptr,
                lng + (l + 1) * HID, lnb + (l + 1) * HID,
                (const float*)nullptr, (const float*)nullptr, 0, NN);
        } else {
            k_gat_fused<<<WB, 256, 0, stream>>>(xl_h, xr_h, epack, rowptr,
                We + l * HID, att + l * HID, bias + l * HID,
                h, (unsigned short*)nullptr, (unsigned short*)nullptr, out,
                lnfg, lnfb, fcW, fcb, 1, NN);
        }
    }
}

// Round 12
// 476.503 us; speedup vs baseline: 1.2626x; 1.0692x over previous
//
#include <hip/hip_runtime.h>
#include <math.h>

#define NN 50000
#define EE 800000
#define FIN 128
#define HID 96
#define NL 4
#define CHUNK 1024

typedef __attribute__((ext_vector_type(8))) short short8;
typedef __attribute__((ext_vector_type(4))) float floatx4;
typedef __attribute__((ext_vector_type(2))) _Float16 half2v;

#define WPREP_L (NL * 2 * 9216)       // 73728
#define WPREP_TOT (WPREP_L + 12288)   // 86016

struct u96 { unsigned x, y, z; };     // 12B payload (global_load_dwordx3)

__device__ __forceinline__ unsigned short f32_to_bf16_rne(float x) {
    unsigned u = __float_as_uint(x);
    unsigned r = (u + 0x7FFFu + ((u >> 16) & 1u)) >> 16;
    return (unsigned short)r;
}
__device__ __forceinline__ float bf16_to_f32(unsigned short h) {
    return __uint_as_float(((unsigned)h) << 16);
}

// ---------------- CSR build ----------------
__global__ void k_hist(const int* __restrict__ dst, int* __restrict__ deg, int E) {
    int e = blockIdx.x * blockDim.x + threadIdx.x;
    if (e < E) atomicAdd(&deg[dst[e]], 1);
}

__global__ void k_scan1(const int* __restrict__ deg, int* __restrict__ partials, int n) {
    __shared__ int lds[256];
    int t = threadIdx.x;
    int base = blockIdx.x * CHUNK + t * 4;
    int s = 0;
    #pragma unroll
    for (int q = 0; q < 4; q++) { int idx = base + q; if (idx < n) s += deg[idx]; }
    lds[t] = s; __syncthreads();
    for (int o = 128; o > 0; o >>= 1) { if (t < o) lds[t] += lds[t + o]; __syncthreads(); }
    if (t == 0) partials[blockIdx.x] = lds[0];
}

__global__ void k_scan_mid(int* partials, int nb, int* rowptr, int n) {
    int lane = threadIdx.x;
    int orig = (lane < nb) ? partials[lane] : 0;
    int v = orig;
    #pragma unroll
    for (int off = 1; off < 64; off <<= 1) {
        int u = __shfl_up(v, off);
        if (lane >= off) v += u;
    }
    if (lane < nb) partials[lane] = v - orig;
    if (lane == 63) rowptr[n] = v;
}

__global__ void k_scan3(const int* __restrict__ deg, const int* __restrict__ partials,
                        int* __restrict__ rowptr, int* __restrict__ cursor, int n) {
    __shared__ int lds[256];
    int t = threadIdx.x;
    int base = blockIdx.x * CHUNK + t * 4;
    int v[4];
    #pragma unroll
    for (int q = 0; q < 4; q++) { int idx = base + q; v[q] = (idx < n) ? deg[idx] : 0; }
    int tsum = v[0] + v[1] + v[2] + v[3];
    lds[t] = tsum; __syncthreads();
    for (int o = 1; o < 256; o <<= 1) {
        int add = (t >= o) ? lds[t - o] : 0;
        __syncthreads();
        lds[t] += add;
        __syncthreads();
    }
    int excl = lds[t] - tsum;
    int run = partials[blockIdx.x] + excl;
    #pragma unroll
    for (int q = 0; q < 4; q++) {
        int idx = base + q;
        if (idx < n) { rowptr[idx] = run; cursor[idx] = run; run += v[q]; }
    }
}

__global__ void k_scatter(const int* __restrict__ src, const int* __restrict__ dst,
                          const float* __restrict__ ew, int* __restrict__ cursor,
                          uint2* __restrict__ epack, int E) {
    int e = blockIdx.x * blockDim.x + threadIdx.x;
    if (e < E) {
        int p = atomicAdd(&cursor[dst[e]], 1);
        epack[p] = make_uint2((unsigned)src[e], __float_as_uint(ew[e]));
    }
}

// ---------------- merged weight prep ----------------
__global__ void k_wprep_all(const float* __restrict__ Wl, const float* __restrict__ Wr,
                            const float* __restrict__ encW,
                            unsigned short* __restrict__ wf_hi, unsigned short* __restrict__ wf_lo,
                            unsigned short* __restrict__ we_hi, unsigned short* __restrict__ we_lo) {
    int t = blockIdx.x * blockDim.x + threadIdx.x;
    if (t < WPREP_L) {
        int within = t % 9216, pair = t / 9216;
        int lr = pair & 1, layer = pair >> 1;
        int j = within & 7;
        int lane = (within >> 3) & 63;
        int cs = within >> 9;
        int s = cs % 3, ct = cs / 3;
        int col = ct * 16 + (lane & 15);
        int k = s * 32 + (lane >> 4) * 8 + j;
        const float* W = (lr ? Wr : Wl) + (size_t)layer * HID * HID;
        float v = W[k * HID + col];
        unsigned short hi = f32_to_bf16_rne(v);
        wf_hi[t] = hi;
        wf_lo[t] = f32_to_bf16_rne(v - bf16_to_f32(hi));
    } else if (t < WPREP_TOT) {
        int u = t - WPREP_L;
        int j = u & 7;
        int lane = (u >> 3) & 63;
        int cs = u >> 9;
        int s = cs & 3, ct = cs >> 2;
        int col = ct * 16 + (lane & 15);
        int k = s * 32 + (lane >> 4) * 8 + j;
        float v = encW[k * HID + col];
        unsigned short hi = f32_to_bf16_rne(v);
        we_hi[u] = hi;
        we_lo[u] = f32_to_bf16_rne(v - bf16_to_f32(hi));
    }
}

// ---------------- encoder via split-bf16 MFMA + fused LN/relu/split epilogue ----------------
__global__ __launch_bounds__(256) void k_enc_mfma(const float* __restrict__ x,
        const unsigned short* __restrict__ we_hi, const unsigned short* __restrict__ we_lo,
        const float* __restrict__ b,
        const float* __restrict__ lng, const float* __restrict__ lnb,
        float* __restrict__ h,
        unsigned short* __restrict__ hn_hi, unsigned short* __restrict__ hn_lo, int n) {
    int t = threadIdx.x;
    int wave = t >> 6, lane = t & 63;
    int quad = lane >> 4, lid = lane & 15;
    int r0 = blockIdx.x * 64 + wave * 16;
    int arow = r0 + lid; if (arow >= n) arow = n - 1;
    short8 aH[4], aL[4];
    #pragma unroll
    for (int s = 0; s < 4; s++) {
        float4 p0 = *(const float4*)(x + (size_t)arow * FIN + s * 32 + quad * 8);
        float4 p1 = *(const float4*)(x + (size_t)arow * FIN + s * 32 + quad * 8 + 4);
        float f[8] = {p0.x, p0.y, p0.z, p0.w, p1.x, p1.y, p1.z, p1.w};
        #pragma unroll
        for (int j = 0; j < 8; j++) {
            unsigned short hi = f32_to_bf16_rne(f[j]);
            aH[s][j] = (short)hi;
            aL[s][j] = (short)f32_to_bf16_rne(f[j] - bf16_to_f32(hi));
        }
    }
    floatx4 o[6];
    #pragma unroll
    for (int ct = 0; ct < 6; ct++) {
        floatx4 acc = {0.f, 0.f, 0.f, 0.f};
        #pragma unroll
        for (int s = 0; s < 4; s++) {
            short8 bH = *(const short8*)(we_hi + ((ct * 4 + s) * 64 + lane) * 8);
            short8 bL = *(const short8*)(we_lo + ((ct * 4 + s) * 64 + lane) * 8);
            acc = __builtin_amdgcn_mfma_f32_16x16x32_bf16(aH[s], bH, acc, 0, 0, 0);
            acc = __builtin_amdgcn_mfma_f32_16x16x32_bf16(aH[s], bL, acc, 0, 0, 0);
            acc = __builtin_amdgcn_mfma_f32_16x16x32_bf16(aL[s], bH, acc, 0, 0, 0);
        }
        float bv = b[ct * 16 + lid];
        #pragma unroll
        for (int rg = 0; rg < 4; rg++) o[ct][rg] = acc[rg] + bv;
    }
    #pragma unroll
    for (int rg = 0; rg < 4; rg++) {
        float s1 = 0.f, s2 = 0.f;
        #pragma unroll
        for (int ct = 0; ct < 6; ct++) { s1 += o[ct][rg]; s2 += o[ct][rg] * o[ct][rg]; }
        #pragma unroll
        for (int off = 1; off < 16; off <<= 1) {
            s1 += __shfl_xor(s1, off);
            s2 += __shfl_xor(s2, off);
        }
        float mu = s1 * (1.f / 96.f);
        float var = s2 * (1.f / 96.f) - mu * mu;
        float rs = rsqrtf(var + 1e-5f);
        int orow = r0 + quad * 4 + rg;
        if (orow < n) {
            #pragma unroll
            for (int ct = 0; ct < 6; ct++) {
                int col = ct * 16 + lid;
                float v = o[ct][rg];
                h[(size_t)orow * HID + col] = v;
                float y = fmaxf((v - mu) * rs * lng[col] + lnb[col], 0.f);
                unsigned short hi = f32_to_bf16_rne(y);
                hn_hi[(size_t)orow * HID + col] = hi;
                hn_lo[(size_t)orow * HID + col] = f32_to_bf16_rne(y - bf16_to_f32(hi));
            }
        }
    }
}

// ---------------- layer GEMMs via split-bf16 MFMA (LDS-staged B, R9 form) ----------------
__global__ __launch_bounds__(256) void k_gemm2_mfma(
        const unsigned short* __restrict__ hn_hi, const unsigned short* __restrict__ hn_lo,
        const unsigned short* __restrict__ wf_hi, const unsigned short* __restrict__ wf_lo,
        const float* __restrict__ bl, const float* __restrict__ br,
        unsigned short* __restrict__ xl_h, unsigned short* __restrict__ xr_h, int n) {
    __shared__ unsigned short lh[9216];
    __shared__ unsigned short ll[9216];
    int t = threadIdx.x;
    int wave = t >> 6, lane = t & 63;
    int quad = lane >> 4, lid = lane & 15;
    int r0 = blockIdx.x * 64 + wave * 16;
    int arow = r0 + lid; if (arow >= n) arow = n - 1;
    short8 aH[3], aL[3];
    #pragma unroll
    for (int s = 0; s < 3; s++) {
        aH[s] = *(const short8*)(hn_hi + (size_t)arow * HID + s * 32 + quad * 8);
        aL[s] = *(const short8*)(hn_lo + (size_t)arow * HID + s * 32 + quad * 8);
    }
    for (int lr = 0; lr < 2; lr++) {
        const unsigned short* sh = wf_hi + lr * 9216;
        const unsigned short* sl = wf_lo + lr * 9216;
        __syncthreads();
        for (int u = t; u < 1152; u += 256) {
            *(short8*)(lh + u * 8) = *(const short8*)(sh + u * 8);
            *(short8*)(ll + u * 8) = *(const short8*)(sl + u * 8);
        }
        __syncthreads();
        const float* bias = lr ? br : bl;
        unsigned short* out = lr ? xr_h : xl_h;
        #pragma unroll
        for (int ct = 0; ct < 6; ct++) {
            floatx4 acc = {0.f, 0.f, 0.f, 0.f};
            #pragma unroll
            for (int s = 0; s < 3; s++) {
                short8 bH = *(const short8*)(lh + ((ct * 3 + s) * 64 + lane) * 8);
                short8 bL = *(const short8*)(ll + ((ct * 3 + s) * 64 + lane) * 8);
                acc = __builtin_amdgcn_mfma_f32_16x16x32_bf16(aH[s], bH, acc, 0, 0, 0);
                acc = __builtin_amdgcn_mfma_f32_16x16x32_bf16(aH[s], bL, acc, 0, 0, 0);
                acc = __builtin_amdgcn_mfma_f32_16x16x32_bf16(aL[s], bH, acc, 0, 0, 0);
            }
            int col = ct * 16 + lid;
            float bv = bias[col];
            #pragma unroll
            for (int rg = 0; rg < 4; rg++) {
                int orow = r0 + quad * 4 + rg;
                if (orow < n) {
                    _Float16 hv = (_Float16)(acc[rg] + bv);
                    out[(size_t)orow * HID + col] = *(unsigned short*)&hv;
                }
            }
        }
    }
}

// ---------------- fused GATv2 + residual + next-layer LN (or final LN+fc) ----------------
// wave = 1 node; 4 groups x 16 lanes; every lane owns 6 dims (16x6=96):
// one dwordx3 (12B fp16) gather per edge, all lanes carry payload.
__global__ __launch_bounds__(256) void k_gat_fused(
        const unsigned short* __restrict__ xl_h, const unsigned short* __restrict__ xr_h,
        const uint2* __restrict__ ep, const int* __restrict__ rowptr,
        const float* __restrict__ We, const float* __restrict__ att, const float* __restrict__ bias,
        float* __restrict__ h,
        unsigned short* __restrict__ hn_hi, unsigned short* __restrict__ hn_lo,
        float* __restrict__ out_final,
        const float* __restrict__ g, const float* __restrict__ bt,
        const float* __restrict__ fcW, const float* __restrict__ fcb,
        int mode, int n) {
    int lane = threadIdx.x & 63;
    int node = blockIdx.x * 4 + (threadIdx.x >> 6);
    if (node >= n) return;
    int grp = lane >> 4, sub = lane & 15;
    int d0 = sub * 6;
    unsigned gOffB = (unsigned)(sub * 12);

    const float LOG2E = 1.4426950408889634f;
    union U6 { u96 u; half2v h2[3]; _Float16 hf[6]; };
    half2v we_h[3], at_h[3], xr_hv[3];
    {
        U6 xrw;
        xrw.u = *(const u96*)((const char*)xr_h + ((unsigned)node * 192u + gOffB));
        float2 a0 = *(const float2*)(We + d0);
        float2 a1 = *(const float2*)(We + d0 + 2);
        float2 a2 = *(const float2*)(We + d0 + 4);
        float2 c0 = *(const float2*)(att + d0);
        float2 c1 = *(const float2*)(att + d0 + 2);
        float2 c2 = *(const float2*)(att + d0 + 4);
        we_h[0] = half2v{(_Float16)a0.x, (_Float16)a0.y};
        we_h[1] = half2v{(_Float16)a1.x, (_Float16)a1.y};
        we_h[2] = half2v{(_Float16)a2.x, (_Float16)a2.y};
        at_h[0] = half2v{(_Float16)(c0.x*LOG2E), (_Float16)(c0.y*LOG2E)};
        at_h[1] = half2v{(_Float16)(c1.x*LOG2E), (_Float16)(c1.y*LOG2E)};
        at_h[2] = half2v{(_Float16)(c2.x*LOG2E), (_Float16)(c2.y*LOG2E)};
        #pragma unroll
        for (int j = 0; j < 3; j++) xr_hv[j] = xrw.h2[j];
    }
    const half2v c02 = half2v{(_Float16)0.2f, (_Float16)0.2f};

    int beg = rowptr[node], end = rowptr[node + 1];
    float ssum = 0.f;
    float acc[6];
    #pragma unroll
    for (int j = 0; j < 6; j++) acc[j] = 0.f;

    auto lq = [&](int p, u96& vraw, float& w, bool& val) {
        int pe = p + grp;
        val = pe < end;
        int pc = val ? pe : end - 1;
        uint2 e = ep[pc];
        w = __uint_as_float(e.y);
        vraw = *(const u96*)((const char*)xl_h + (e.x * 192u + gOffB));
    };
    auto proc = [&](const u96& vraw, float w, bool val) {
        U6 cv; cv.u = vraw;
        _Float16 wh = (_Float16)w;
        half2v w2 = half2v{wh, wh};
        float q = 0.f;
        #pragma unroll
        for (int j = 0; j < 3; j++) {
            half2v t = cv.h2[j] + xr_hv[j];
            t = w2 * we_h[j] + t;
            half2v t2 = t * c02;
            t = __builtin_elementwise_max(t, t2);
#if __has_builtin(__builtin_amdgcn_fdot2)
            q = __builtin_amdgcn_fdot2(t, at_h[j], q, false);
#else
            q = fmaf((float)t[0], (float)at_h[j][0], q);
            q = fmaf((float)t[1], (float)at_h[j][1], q);
#endif
        }
        q += __shfl_xor(q, 1); q += __shfl_xor(q, 2);
        q += __shfl_xor(q, 4); q += __shfl_xor(q, 8);
        float e = val ? exp2f(q) : 0.f;
        ssum += e;
        #pragma unroll
        for (int j = 0; j < 6; j++) acc[j] = fmaf((float)cv.hf[j], e, acc[j]);
    };

    if (beg < end) {
        u96 vA, vB; float wA, wB; bool okA, okB;
        lq(beg,     vA, wA, okA);
        lq(beg + 4, vB, wB, okB);
        for (int p = beg; p < end; p += 8) {
            proc(vA, wA, okA);
            lq(p + 8, vA, wA, okA);
            proc(vB, wB, okB);
            lq(p + 12, vB, wB, okB);
        }
    }

    ssum += __shfl_xor(ssum, 16); ssum += __shfl_xor(ssum, 32);
    #pragma unroll
    for (int j = 0; j < 6; j++) {
        acc[j] += __shfl_xor(acc[j], 16);
        acc[j] += __shfl_xor(acc[j], 32);
    }
    float inv = 1.f / (ssum + 1e-16f);

    float nh[6];
    float s1 = 0.f, s2 = 0.f;
    {
        float2 h0 = *(const float2*)(h + (size_t)node * HID + d0);
        float2 h1 = *(const float2*)(h + (size_t)node * HID + d0 + 2);
        float2 h2 = *(const float2*)(h + (size_t)node * HID + d0 + 4);
        float2 b0 = *(const float2*)(bias + d0);
        float2 b1 = *(const float2*)(bias + d0 + 2);
        float2 b2 = *(const float2*)(bias + d0 + 4);
        float hv[6] = {h0.x, h0.y, h1.x, h1.y, h2.x, h2.y};
        float bv[6] = {b0.x, b0.y, b1.x, b1.y, b2.x, b2.y};
        #pragma unroll
        for (int j = 0; j < 6; j++) {
            nh[j] = hv[j] + acc[j] * inv + bv[j];
            s1 += nh[j];
            s2 += nh[j] * nh[j];
        }
    }
    #pragma unroll
    for (int off = 1; off < 16; off <<= 1) {
        s1 += __shfl_xor(s1, off);
        s2 += __shfl_xor(s2, off);
    }
    float mu = s1 * (1.f / 96.f);
    float var = s2 * (1.f / 96.f) - mu * mu;
    float rs = rsqrtf(var + 1e-5f);

    if (mode == 0) {
        if (grp == 0) {
            float2 g0 = *(const float2*)(g + d0);
            float2 g1 = *(const float2*)(g + d0 + 2);
            float2 g2 = *(const float2*)(g + d0 + 4);
            float2 t0 = *(const float2*)(bt + d0);
            float2 t1 = *(const float2*)(bt + d0 + 2);
            float2 t2 = *(const float2*)(bt + d0 + 4);
            float gv[6] = {g0.x, g0.y, g1.x, g1.y, g2.x, g2.y};
            float tv[6] = {t0.x, t0.y, t1.x, t1.y, t2.x, t2.y};
            *(float2*)(h + (size_t)node * HID + d0)     = make_float2(nh[0], nh[1]);
            *(float2*)(h + (size_t)node * HID + d0 + 2) = make_float2(nh[2], nh[3]);
            *(float2*)(h + (size_t)node * HID + d0 + 4) = make_float2(nh[4], nh[5]);
            unsigned hi[3], lo[3];
            #pragma unroll
            for (int j = 0; j < 3; j++) {
                float ox = fmaxf((nh[2*j]   - mu) * rs * gv[2*j]   + tv[2*j],   0.f);
                float oy = fmaxf((nh[2*j+1] - mu) * rs * gv[2*j+1] + tv[2*j+1], 0.f);
                unsigned short hx = f32_to_bf16_rne(ox), hy = f32_to_bf16_rne(oy);
                unsigned short lx = f32_to_bf16_rne(ox - bf16_to_f32(hx));
                unsigned short ly = f32_to_bf16_rne(oy - bf16_to_f32(hy));
                hi[j] = (unsigned)hx | ((unsigned)hy << 16);
                lo[j] = (unsigned)lx | ((unsigned)ly << 16);
            }
            u96 wh = {hi[0], hi[1], hi[2]};
            u96 wl = {lo[0], lo[1], lo[2]};
            *(u96*)((char*)hn_hi + 2 * ((size_t)node * HID + d0)) = wh;
            *(u96*)((char*)hn_lo + 2 * ((size_t)node * HID + d0)) = wl;
        }
    } else {
        float pacc = 0.f;
        {
            float2 g0 = *(const float2*)(g + d0);
            float2 g1 = *(const float2*)(g + d0 + 2);
            float2 g2 = *(const float2*)(g + d0 + 4);
            float2 t0 = *(const float2*)(bt + d0);
            float2 t1 = *(const float2*)(bt + d0 + 2);
            float2 t2 = *(const float2*)(bt + d0 + 4);
            float2 w0 = *(const float2*)(fcW + d0);
            float2 w1 = *(const float2*)(fcW + d0 + 2);
            float2 w2 = *(const float2*)(fcW + d0 + 4);
            float gv[6] = {g0.x, g0.y, g1.x, g1.y, g2.x, g2.y};
            float tv[6] = {t0.x, t0.y, t1.x, t1.y, t2.x, t2.y};
            float wv[6] = {w0.x, w0.y, w1.x, w1.y, w2.x, w2.y};
            #pragma unroll
            for (int j = 0; j < 6; j++) {
                float y = fmaxf((nh[j] - mu) * rs * gv[j] + tv[j], 0.f);
                pacc = fmaf(y, wv[j], pacc);
            }
        }
        #pragma unroll
        for (int off = 1; off < 16; off <<= 1) pacc += __shfl_xor(pacc, off);
        if (lane == 0) out_final[node] = pacc + fcb[0];
    }
}

extern "C" void kernel_launch(void* const* d_in, const int* in_sizes, int n_in,
                              void* d_out, int out_size, void* d_ws, size_t ws_size,
                              hipStream_t stream) {
    const float* x    = (const float*)d_in[0];
    const int*   ei   = (const int*)  d_in[1];
    const float* ew   = (const float*)d_in[2];
    const float* encW = (const float*)d_in[3];
    const float* encB = (const float*)d_in[4];
    const float* Wl   = (const float*)d_in[5];
    const float* bl   = (const float*)d_in[6];
    const float* Wr   = (const float*)d_in[7];
    const float* br   = (const float*)d_in[8];
    const float* We   = (const float*)d_in[9];
    const float* att  = (const float*)d_in[10];
    const float* bias = (const float*)d_in[11];
    const float* lng  = (const float*)d_in[12];
    const float* lnb  = (const float*)d_in[13];
    const float* lnfg = (const float*)d_in[14];
    const float* lnfb = (const float*)d_in[15];
    const float* fcW  = (const float*)d_in[16];
    const float* fcb  = (const float*)d_in[17];
    float* out = (float*)d_out;

    const int* src = ei;
    const int* dst = ei + EE;

    char* ws = (char*)d_ws;
    size_t off = 0;
    auto alloc = [&](size_t bytes) -> void* {
        void* p = ws + off;
        off += (bytes + 255) & ~(size_t)255;
        return p;
    };
    float* h      = (float*)alloc((size_t)NN * HID * 4);
    unsigned short* xl_h  = (unsigned short*)alloc((size_t)NN * HID * 2 + 256);
    unsigned short* xr_h  = (unsigned short*)alloc((size_t)NN * HID * 2 + 256);
    unsigned short* hn_hi = (unsigned short*)alloc((size_t)NN * HID * 2);
    unsigned short* hn_lo = (unsigned short*)alloc((size_t)NN * HID * 2);
    unsigned short* wf_hi = (unsigned short*)alloc((size_t)WPREP_L * 2);
    unsigned short* wf_lo = (unsigned short*)alloc((size_t)WPREP_L * 2);
    unsigned short* we_hi = (unsigned short*)alloc(12288 * 2);
    unsigned short* we_lo = (unsigned short*)alloc(12288 * 2);
    int*   deg    = (int*)  alloc((size_t)NN * 4);
    int*   rowptr = (int*)  alloc((size_t)(NN + 1) * 4);
    int*   cursor = (int*)  alloc((size_t)NN * 4);
    uint2* epack  = (uint2*)alloc((size_t)EE * 8);
    int*   parts  = (int*)  alloc(256 * 4);

    const int NB = (NN + CHUNK - 1) / CHUNK;   // 49
    const int EB = (EE + 255) / 256;           // 3125
    const int MB = (NN + 63) / 64;             // 782
    const int WB = (NN + 3) / 4;               // 12500

    // CSR build
    hipMemsetAsync(deg, 0, (size_t)NN * 4, stream);
    k_hist<<<EB, 256, 0, stream>>>(dst, deg, EE);
    k_scan1<<<NB, 256, 0, stream>>>(deg, parts, NN);
    k_scan_mid<<<1, 64, 0, stream>>>(parts, NB, rowptr, NN);
    k_scan3<<<NB, 256, 0, stream>>>(deg, parts, rowptr, cursor, NN);
    k_scatter<<<EB, 256, 0, stream>>>(src, dst, ew, cursor, epack, EE);

    // weight prep
    k_wprep_all<<<(WPREP_TOT + 255) / 256, 256, 0, stream>>>(Wl, Wr, encW, wf_hi, wf_lo, we_hi, we_lo);

    // encoder (+fused first LN)
    k_enc_mfma<<<MB, 256, 0, stream>>>(x, we_hi, we_lo, encB, lng, lnb, h, hn_hi, hn_lo, NN);

    for (int l = 0; l < NL; l++) {
        k_gemm2_mfma<<<MB, 256, 0, stream>>>(hn_hi, hn_lo,
            wf_hi + (size_t)l * 2 * 9216, wf_lo + (size_t)l * 2 * 9216,
            bl + l * HID, br + l * HID, xl_h, xr_h, NN);
        if (l < NL - 1) {
            k_gat_fused<<<WB, 256, 0, stream>>>(xl_h, xr_h, epack, rowptr,
                We + l * HID, att + l * HID, bias + l * HID,
                h, hn_hi, hn_lo, (float*)nullptr,
                lng + (l + 1) * HID, lnb + (l + 1) * HID,
                (const float*)nullptr, (const float*)nullptr, 0, NN);
        } else {
            k_gat_fused<<<WB, 256, 0, stream>>>(xl_h, xr_h, epack, rowptr,
                We + l * HID, att + l * HID, bias + l * HID,
                h, (unsigned short*)nullptr, (unsigned short*)nullptr, out,
                lnfg, lnfb, fcW, fcb, 1, NN);
        }
    }
}